// Round 11
// baseline (95.428 us; speedup 1.0000x reference)
//
#include <hip/hip_runtime.h>
#include <math.h>

#define NHEADS 16
#define HS     128
#define NOPT   512
#define TB     128      // tokens per block (4 waves x 32)
#define OC     32       // options per image sub-chunk
#define NCH    16       // sub-chunks per head
#define NITER  8        // 2 sub-chunks (64 options) per iteration
#define EMB    2048
#define LOG2E  1.44269504088896340736f
#define THRD   11.0f    // defer-max threshold (log2 units)

typedef short bf16x8 __attribute__((ext_vector_type(8)));
typedef _Float16 f16x8 __attribute__((ext_vector_type(8)));
typedef unsigned short u16x8 __attribute__((ext_vector_type(8)));
typedef float f32x4 __attribute__((ext_vector_type(4)));
typedef float f32x16 __attribute__((ext_vector_type(16)));
typedef unsigned u32x4 __attribute__((ext_vector_type(4)));

__device__ __forceinline__ unsigned short f2bf(float f) {
    union { float f; unsigned u; } v; v.f = f;
    unsigned r = v.u + 0x7FFFu + ((v.u >> 16) & 1u);
    return (unsigned short)(r >> 16);
}
__device__ __forceinline__ float bf2f(unsigned short h) {
    union { unsigned u; float f; } v; v.u = ((unsigned)h) << 16;
    return v.f;
}
__device__ __forceinline__ unsigned short f2h(float f) {   // RNE f32->f16 bits
    const _Float16 h = (_Float16)f;
    return __builtin_bit_cast(unsigned short, h);
}
__device__ __forceinline__ unsigned pkrtz(float lo, float hi) {
    unsigned r;
    asm("v_cvt_pkrtz_f16_f32 %0, %1, %2" : "=v"(r) : "v"(lo), "v"(hi));
    return r;
}
__device__ __forceinline__ void pl32swap(unsigned &a, unsigned &b) {
    asm volatile("v_permlane32_swap_b32 %0, %1" : "+v"(a), "+v"(b));
}
__device__ __forceinline__ f32x16 mfma32h(f16x8 a, f16x8 b, f32x16 c) {
    return __builtin_amdgcn_mfma_f32_32x32x16_f16(a, b, c, 0, 0, 0);
}

// ------------- workspace image layout (ushorts, f16 bits), FRAGMENT ORDER ----
// W': [h][sub][kb][lane][8]  — lane l's QK A-operand packet for k-block kb.
//     (pre-scaled by invT*log2e).  4096 elems / sub-chunk = 8 KB.
// C : [h][sub][nt][q][lane][8] — lane l's PV B-operand packet for output block
//     nt, option-half q.            4096 elems / sub-chunk = 8 KB.
// Every wave operand load = ONE coalesced 1KB global_load_dwordx4. No LDS.
#define SUBELEMS 4096
#define WS_C0  (NHEADS * NCH * SUBELEMS)
#define WS_TOTAL_BYTES ((size_t)(WS_C0 + NHEADS * NCH * SUBELEMS) * 2) // 4 MB

// ============ prep: f32 -> fragment-order f16 images ============
__global__ __launch_bounds__(256) void vq_prep(const float* __restrict__ W,
                                               const float* __restrict__ C,
                                               const float* __restrict__ temp,
                                               unsigned short* __restrict__ ws)
{
    const int b = blockIdx.x, t = threadIdx.x;
    if (b < NHEADS * NCH) {                 // W sub-chunk (scaled, f16)
        const float scW = (1.0f / temp[0]) * LOG2E;
        const float* src = W + (size_t)b * OC * HS;
        unsigned short* dst = ws + (size_t)b * SUBELEMS;
        for (int k4 = 0; k4 < 16; ++k4) {
            const int e = k4 * 256 + t;     // 4096 elems
            const int opt = e >> 7, k = e & 127;
            const int kb = k >> 4, hf = (k >> 3) & 1, j = k & 7;
            const int l = hf * 32 + opt;    // opt == la (0..31)
            dst[kb * 512 + l * 8 + j] = f2h(src[e] * scW);
        }
    } else {                                // C sub-chunk -> PV fragment order
        const int b2 = b - NHEADS * NCH;
        const float* src = C + (size_t)b2 * OC * HS;
        unsigned short* dst = ws + WS_C0 + (size_t)b2 * SUBELEMS;
        for (int k4 = 0; k4 < 16; ++k4) {
            const int e = k4 * 256 + t;
            const int opt = e >> 7, a = e & 127;
            const int q = opt >> 4, hf = (opt >> 3) & 1, j = opt & 7;
            const int nt = a >> 5, l = hf * 32 + (a & 31);
            dst[(nt * 2 + q) * 512 + l * 8 + j] = f2h(src[e]);
        }
    }
}

// ============ main: barrier-free, LDS-free, all operands direct from L2 =====
// R10 residual was the stage->vmcnt->barrier critical path (2 rendezvous/iter
// for 4 waves). Fragment-order images make every operand load a coalesced 1KB
// wave read from the L2-resident image -> waves fully independent, compiler
// free to hoist loads across iterations. Numerics identical to R10.
__global__ __launch_bounds__(256, 2) void vq_main(
    const float* __restrict__ x, const unsigned short* __restrict__ ws,
    float* __restrict__ out)
{
    const int t = threadIdx.x, l = t & 63, w = t >> 6;
    const int la = l & 31, hf = l >> 5;
    const int b = blockIdx.x;
    const int head = ((b & 7) << 1) | ((b >> 3) & 1);   // 2 heads per XCD
    const int n0 = (b >> 4) * TB;

    const unsigned short* __restrict__ wimg = ws + (size_t)(head * NCH) * SUBELEMS;
    const unsigned short* __restrict__ cimg = ws + WS_C0 + (size_t)(head * NCH) * SUBELEMS;
    const int l8 = l * 8;

    // ---- x row as f16 B-fragments (32 VGPR) ----
    f16x8 xf[8];
    {
        const float* xr = x + (size_t)(n0 + w * 32 + la) * EMB + head * HS + hf * 8;
        #pragma unroll
        for (int kb = 0; kb < 8; ++kb) {
            const float4 v0 = *(const float4*)(xr + kb * 16);
            const float4 v1 = *(const float4*)(xr + kb * 16 + 4);
            const float vv[8] = {v0.x, v0.y, v0.z, v0.w, v1.x, v1.y, v1.z, v1.w};
            u16x8 hh;
            #pragma unroll
            for (int j = 0; j < 8; ++j) hh[j] = f2h(vv[j]);
            xf[kb] = __builtin_bit_cast(f16x8, hh);
        }
    }

    f32x16 O0 = (f32x16)0.0f, O1 = (f32x16)0.0f, O2 = (f32x16)0.0f, O3 = (f32x16)0.0f;
    float M = -1.0e30f, sacc = 0.0f;

    for (int cc = 0; cc < NITER; ++cc) {
        const int sub0 = 2 * cc, sub1 = 2 * cc + 1;

        // ---- QK^T: S0 (sub0), S1 (sub1); 2 chains each; operands straight
        //      from the fragment-order image (coalesced 1KB wave loads) ----
        f32x16 s0a = (f32x16)0.0f, s0b = (f32x16)0.0f;
        f32x16 s1a = (f32x16)0.0f, s1b = (f32x16)0.0f;
        const unsigned short* __restrict__ w0p = wimg + (size_t)sub0 * SUBELEMS;
        const unsigned short* __restrict__ w1p = wimg + (size_t)sub1 * SUBELEMS;
        #pragma unroll
        for (int kb = 0; kb < 8; ++kb) {
            const f16x8 w0 = *(const f16x8*)&w0p[kb * 512 + l8];
            const f16x8 w1 = *(const f16x8*)&w1p[kb * 512 + l8];
            if (kb & 1) { s0b = mfma32h(w0, xf[kb], s0b); s1b = mfma32h(w1, xf[kb], s1b); }
            else        { s0a = mfma32h(w0, xf[kb], s0a); s1a = mfma32h(w1, xf[kb], s1a); }
        }
        f32x16 S0 = s0a + s0b;
        f32x16 S1 = s1a + s1b;

        // ---- online softmax over 64 options (one check per iteration) ----
        float cmax = fmaxf(S0[0], S1[0]);
        #pragma unroll
        for (int i = 1; i < 16; ++i) cmax = fmaxf(fmaxf(cmax, S0[i]), S1[i]);
        cmax = fmaxf(cmax, __shfl_xor(cmax, 32));
        if (__any(cmax > M + THRD)) {          // rare rescale (defer-max, T13)
            const float Mn = fmaxf(M, cmax);
            const float fr = exp2f(M - Mn);    // first iteration: exp2(-1e30)=0
            M = Mn;
            sacc *= fr;
            #pragma unroll
            for (int q = 0; q < 16; ++q) {
                const int row = (q & 3) + 8 * (q >> 2) + 4 * hf;
                const float f = __shfl(fr, row);
                O0[q] *= f; O1[q] *= f; O2[q] *= f; O3[q] *= f;
            }
        }
        #pragma unroll
        for (int q = 0; q < 16; ++q) { S0[q] = exp2f(S0[q] - M); S1[q] = exp2f(S1[q] - M); }
        {   // tree sum over both halves
            float s8[8];
            #pragma unroll
            for (int i = 0; i < 8; ++i)
                s8[i] = (S0[2 * i] + S0[2 * i + 1]) + (S1[2 * i] + S1[2 * i + 1]);
            sacc += ((s8[0] + s8[1]) + (s8[2] + s8[3])) +
                    ((s8[4] + s8[5]) + (s8[6] + s8[7]));
        }

        // ---- P -> f16 A-fragments in-register (verified T12 recipe, x2) ----
        unsigned pk0 = pkrtz(S0[0],  S0[1]),  pk1 = pkrtz(S0[2],  S0[3]);
        unsigned pk2 = pkrtz(S0[4],  S0[5]),  pk3 = pkrtz(S0[6],  S0[7]);
        unsigned pk4 = pkrtz(S0[8],  S0[9]),  pk5 = pkrtz(S0[10], S0[11]);
        unsigned pk6 = pkrtz(S0[12], S0[13]), pk7 = pkrtz(S0[14], S0[15]);
        pl32swap(pk0, pk2); pl32swap(pk1, pk3);
        pl32swap(pk4, pk6); pl32swap(pk5, pk7);
        const f16x8 pa0 = __builtin_bit_cast(f16x8, (u32x4){pk0, pk1, pk2, pk3});
        const f16x8 pa1 = __builtin_bit_cast(f16x8, (u32x4){pk4, pk5, pk6, pk7});
        unsigned qk0 = pkrtz(S1[0],  S1[1]),  qk1 = pkrtz(S1[2],  S1[3]);
        unsigned qk2 = pkrtz(S1[4],  S1[5]),  qk3 = pkrtz(S1[6],  S1[7]);
        unsigned qk4 = pkrtz(S1[8],  S1[9]),  qk5 = pkrtz(S1[10], S1[11]);
        unsigned qk6 = pkrtz(S1[12], S1[13]), qk7 = pkrtz(S1[14], S1[15]);
        pl32swap(qk0, qk2); pl32swap(qk1, qk3);
        pl32swap(qk4, qk6); pl32swap(qk5, qk7);
        const f16x8 pa2 = __builtin_bit_cast(f16x8, (u32x4){qk0, qk1, qk2, qk3});
        const f16x8 pa3 = __builtin_bit_cast(f16x8, (u32x4){qk4, qk5, qk6, qk7});

        // ---- PV: O += P · C ; operands direct from fragment-order C image ----
        const unsigned short* __restrict__ c0p = cimg + (size_t)sub0 * SUBELEMS;
        const unsigned short* __restrict__ c1p = cimg + (size_t)sub1 * SUBELEMS;
        #pragma unroll
        for (int nt = 0; nt < 4; ++nt) {
            f32x16& O = (nt == 0) ? O0 : (nt == 1) ? O1 : (nt == 2) ? O2 : O3;
            O = mfma32h(pa0, *(const f16x8*)&c0p[(nt * 2 + 0) * 512 + l8], O);
            O = mfma32h(pa1, *(const f16x8*)&c0p[(nt * 2 + 1) * 512 + l8], O);
            O = mfma32h(pa2, *(const f16x8*)&c1p[(nt * 2 + 0) * 512 + l8], O);
            O = mfma32h(pa3, *(const f16x8*)&c1p[(nt * 2 + 1) * 512 + l8], O);
        }
    }

    // ---- epilogue: normalize by 1/sum, coalesced stores ----
    const float stot = sacc + __shfl_xor(sacc, 32);
    const float rs = 1.0f / stot;
    #pragma unroll
    for (int q = 0; q < 16; ++q) {
        const int row = (q & 3) + 8 * (q >> 2) + 4 * hf;
        const float rq = __shfl(rs, row);
        float* op = out + (size_t)(n0 + w * 32 + row) * EMB + head * HS + la;
        op[0]  = O0[q] * rq;
        op[32] = O1[q] * rq;
        op[64] = O2[q] * rq;
        op[96] = O3[q] * rq;
    }
}

// ============ fallback (Round-2 kernel, no workspace needed) ============
__global__ __launch_bounds__(256, 2) void vq_fwd_mfma(
    const float* __restrict__ x, const float* __restrict__ W,
    const float* __restrict__ C, const float* __restrict__ temp,
    float* __restrict__ out)
{
    __shared__ unsigned short xh_lds[64 * HS];
    __shared__ unsigned short xl_lds[64 * HS];
    __shared__ unsigned short wst[2][64 * HS];
    __shared__ unsigned short p_lds[4][16 * 64];

    const int t = threadIdx.x, l = t & 63, w = t >> 6, lr = l & 15, lk = l >> 4;
    const int b = blockIdx.x;
    const int h = ((b & 7) << 1) | ((b >> 3) & 1);
    const int n0 = (b >> 4) * 64;
    const float invT = 1.0f / temp[0];

    #pragma unroll
    for (int kk = 0; kk < 4; ++kk) {
        const int g = t + 256 * kk;
        const int row = g >> 4, c8 = (g & 15) * 8;
        const float* src = x + (size_t)(n0 + row) * EMB + h * HS + c8;
        const float4 v0 = *(const float4*)src;
        const float4 v1 = *(const float4*)(src + 4);
        float vv[8] = {v0.x, v0.y, v0.z, v0.w, v1.x, v1.y, v1.z, v1.w};
        u16x8 hh, ll;
        #pragma unroll
        for (int j = 0; j < 8; ++j) {
            const unsigned short hb = f2bf(vv[j]);
            hh[j] = hb; ll[j] = f2bf(vv[j] - bf2f(hb));
        }
        const int idx = row * HS + (c8 ^ ((row & 7) << 3));
        *(u16x8*)&xh_lds[idx] = hh;
        *(u16x8*)&xl_lds[idx] = ll;
    }

    f32x4 acc[32];
    #pragma unroll
    for (int i = 0; i < 32; ++i) acc[i] = f32x4{0.f, 0.f, 0.f, 0.f};
    bf16x8 axh[4], axl[4];

    #pragma unroll
    for (int c = 0; c < 8; ++c) {
        if (c) __syncthreads();
        #pragma unroll
        for (int kk = 0; kk < 4; ++kk) {
            const int g = t + 256 * kk;
            const int row = g >> 4, c8 = (g & 15) * 8;
            const float* src = W + ((size_t)h * NOPT + c * 64 + row) * HS + c8;
            const float4 v0 = *(const float4*)src;
            const float4 v1 = *(const float4*)(src + 4);
            float vv[8] = {v0.x, v0.y, v0.z, v0.w, v1.x, v1.y, v1.z, v1.w};
            u16x8 hh, ll;
            #pragma unroll
            for (int j = 0; j < 8; ++j) {
                const unsigned short hb = f2bf(vv[j]);
                hh[j] = hb; ll[j] = f2bf(vv[j] - bf2f(hb));
            }
            const int idx = row * HS + (c8 ^ ((row & 7) << 3));
            *(u16x8*)&wst[0][idx] = hh;
            *(u16x8*)&wst[1][idx] = ll;
        }
        __syncthreads();
        if (c == 0) {
            const int arow = w * 16 + lr;
            #pragma unroll
            for (int ks = 0; ks < 4; ++ks) {
                const int ai = arow * HS + ((lk * 8 + ks * 32) ^ ((arow & 7) << 3));
                axh[ks] = *(const bf16x8*)&xh_lds[ai];
                axl[ks] = *(const bf16x8*)&xl_lds[ai];
            }
        }
        #pragma unroll
        for (int nt = 0; nt < 4; ++nt) {
            const int brow = nt * 16 + lr;
            #pragma unroll
            for (int ks = 0; ks < 4; ++ks) {
                const int bi = brow * HS + ((lk * 8 + ks * 32) ^ ((brow & 7) << 3));
                const bf16x8 bh = *(const bf16x8*)&wst[0][bi];
                const bf16x8 bl = *(const bf16x8*)&wst[1][bi];
                acc[c*4+nt] = __builtin_amdgcn_mfma_f32_16x16x32_bf16(axh[ks], bh, acc[c*4+nt], 0, 0, 0);
                acc[c*4+nt] = __builtin_amdgcn_mfma_f32_16x16x32_bf16(axl[ks], bh, acc[c*4+nt], 0, 0, 0);
                acc[c*4+nt] = __builtin_amdgcn_mfma_f32_16x16x32_bf16(axh[ks], bl, acc[c*4+nt], 0, 0, 0);
            }
        }
    }

    float mx[4], rsn[4];
    #pragma unroll
    for (int r = 0; r < 4; ++r) {
        float m = -3.0e38f;
        #pragma unroll
        for (int i = 0; i < 32; ++i) m = fmaxf(m, acc[i][r]);
        m *= invT;
        #pragma unroll
        for (int s = 1; s < 16; s <<= 1) m = fmaxf(m, __shfl_xor(m, s));
        float sum = 0.f;
        #pragma unroll
        for (int i = 0; i < 32; ++i) sum += exp2f((acc[i][r] * invT - m) * LOG2E);
        #pragma unroll
        for (int s = 1; s < 16; s <<= 1) sum += __shfl_xor(sum, s);
        mx[r] = m; rsn[r] = 1.0f / sum;
    }

    f32x4 oacc[8];
    #pragma unroll
    for (int i = 0; i < 8; ++i) oacc[i] = f32x4{0.f, 0.f, 0.f, 0.f};
    const int pr_ = t & 31, ag = t >> 5;
    #pragma unroll
    for (int c = 0; c < 8; ++c) {
        __syncthreads();
        {
            const float* c0p = C + ((size_t)h * NOPT + c * 64 + 2 * pr_) * HS + ag * 16;
            float va[16], vb[16];
            #pragma unroll
            for (int q = 0; q < 4; ++q) {
                const float4 u0 = ((const float4*)c0p)[q];
                const float4 u1 = ((const float4*)(c0p + HS))[q];
                va[q*4+0] = u0.x; va[q*4+1] = u0.y; va[q*4+2] = u0.z; va[q*4+3] = u0.w;
                vb[q*4+0] = u1.x; vb[q*4+1] = u1.y; vb[q*4+2] = u1.z; vb[q*4+3] = u1.w;
            }
            unsigned* ct32 = (unsigned*)&wst[0][0];
            #pragma unroll
            for (int j = 0; j < 16; ++j) {
                const int a = ag * 16 + j;
                const unsigned pkv = (unsigned)f2bf(va[j]) | ((unsigned)f2bf(vb[j]) << 16);
                ct32[a * 32 + (pr_ ^ ((a & 7) << 2))] = pkv;
            }
        }
        #pragma unroll
        for (int nt = 0; nt < 4; ++nt) {
            #pragma unroll
            for (int r = 0; r < 4; ++r) {
                const float p = exp2f((acc[c*4+nt][r] * invT - mx[r]) * LOG2E);
                const int prow = lk * 4 + r;
                const int pcol = nt * 16 + lr;
                p_lds[w][prow * 64 + (pcol ^ ((prow & 7) << 3))] = f2bf(p);
            }
        }
        __syncthreads();
        #pragma unroll
        for (int ks = 0; ks < 2; ++ks) {
            const int ai = lr * 64 + ((lk * 8 + ks * 32) ^ ((lr & 7) << 3));
            const bf16x8 pa = *(const bf16x8*)&p_lds[w][ai];
            #pragma unroll
            for (int nt = 0; nt < 8; ++nt) {
                const int brow = nt * 16 + lr;
                const int bi = brow * 64 + ((lk * 8 + ks * 32) ^ ((brow & 7) << 3));
                const bf16x8 cbv = *(const bf16x8*)&wst[0][bi];
                oacc[nt] = __builtin_amdgcn_mfma_f32_16x16x32_bf16(pa, cbv, oacc[nt], 0, 0, 0);
            }
        }
    }

    #pragma unroll
    for (int nt = 0; nt < 8; ++nt) {
        #pragma unroll
        for (int r = 0; r < 4; ++r) {
            const int tok = n0 + w * 16 + lk * 4 + r;
            out[(size_t)tok * EMB + h * HS + nt * 16 + lr] = oacc[nt][r] * rsn[r];
        }
    }
}

extern "C" void kernel_launch(void* const* d_in, const int* in_sizes, int n_in,
                              void* d_out, int out_size, void* d_ws, size_t ws_size,
                              hipStream_t stream) {
    const float* x = (const float*)d_in[0];
    const float* W = (const float*)d_in[1];
    const float* C = (const float*)d_in[2];
    const float* T = (const float*)d_in[3];
    float* out     = (float*)d_out;

    const int ntok = in_sizes[0] / EMB;   // 8192

    if (ws_size >= WS_TOTAL_BYTES) {
        hipLaunchKernelGGL(vq_prep, dim3(NHEADS * NCH * 2), dim3(256), 0, stream,
                           W, C, T, (unsigned short*)d_ws);
        const int nblk = (ntok / TB) * NHEADS;   // 1024
        hipLaunchKernelGGL(vq_main, dim3(nblk), dim3(256), 0, stream,
                           x, (const unsigned short*)d_ws, out);
    } else {
        const int nblk = (ntok / 64) * NHEADS;   // 2048
        hipLaunchKernelGGL(vq_fwd_mfma, dim3(nblk), dim3(256), 0, stream,
                           x, W, C, T, out);
    }
}

// Round 12
// 72.541 us; speedup vs baseline: 1.3155x; 1.3155x over previous
//
#include <hip/hip_runtime.h>
#include <math.h>

#define NHEADS 16
#define HS     128
#define NOPT   512
#define TB     128      // tokens per block (4 waves x 32)
#define OC     32       // options per image sub-chunk
#define NCH    16       // sub-chunks per head
#define NITER  8        // 2 sub-chunks (64 options) per iteration
#define EMB    2048
#define LOG2E  1.44269504088896340736f
#define THRD   11.0f    // defer-max threshold (log2 units)

typedef short bf16x8 __attribute__((ext_vector_type(8)));
typedef _Float16 f16x8 __attribute__((ext_vector_type(8)));
typedef unsigned short u16x8 __attribute__((ext_vector_type(8)));
typedef float f32x4 __attribute__((ext_vector_type(4)));
typedef float f32x16 __attribute__((ext_vector_type(16)));
typedef unsigned u32x4 __attribute__((ext_vector_type(4)));

__device__ __forceinline__ unsigned short f2bf(float f) {
    union { float f; unsigned u; } v; v.f = f;
    unsigned r = v.u + 0x7FFFu + ((v.u >> 16) & 1u);
    return (unsigned short)(r >> 16);
}
__device__ __forceinline__ float bf2f(unsigned short h) {
    union { unsigned u; float f; } v; v.u = ((unsigned)h) << 16;
    return v.f;
}
__device__ __forceinline__ unsigned short f2h(float f) {   // RNE f32->f16 bits
    const _Float16 h = (_Float16)f;
    return __builtin_bit_cast(unsigned short, h);
}
__device__ __forceinline__ void gll16(const void* gptr, void* lptr) {
    __builtin_amdgcn_global_load_lds(
        (const __attribute__((address_space(1))) void*)gptr,
        (__attribute__((address_space(3))) void*)lptr,
        16, 0, 0);
}
__device__ __forceinline__ unsigned pkrtz(float lo, float hi) {
    unsigned r;
    asm("v_cvt_pkrtz_f16_f32 %0, %1, %2" : "=v"(r) : "v"(lo), "v"(hi));
    return r;
}
__device__ __forceinline__ void pl32swap(unsigned &a, unsigned &b) {
    asm volatile("v_permlane32_swap_b32 %0, %1" : "+v"(a), "+v"(b));
}
__device__ __forceinline__ f32x16 mfma32h(f16x8 a, f16x8 b, f32x16 c) {
    return __builtin_amdgcn_mfma_f32_32x32x16_f16(a, b, c, 0, 0, 0);
}

// ------------- workspace image layout (ushorts, f16 bits), FRAGMENT ORDER ----
// (verified correct by R11's pass)
// W': [h][sub][kb][lane][8]   — lane l's QK A-operand packet, pre-scaled by
//                               invT*log2e. 4096 elems / sub-chunk = 8 KB.
// C : [h][sub][nt*2+q][lane][8] — lane l's PV B-operand packet.
// Staged through LDS byte-identically -> every operand read is a LINEAR
// ds_read_b128 (lane -> base + l*16): conflict-free, near-zero address math.
#define SUBELEMS 4096
#define WS_C0  (NHEADS * NCH * SUBELEMS)
#define WS_TOTAL_BYTES ((size_t)(WS_C0 + NHEADS * NCH * SUBELEMS) * 2) // 4 MB

// ============ prep: f32 -> fragment-order f16 images (R11, verified) ========
__global__ __launch_bounds__(256) void vq_prep(const float* __restrict__ W,
                                               const float* __restrict__ C,
                                               const float* __restrict__ temp,
                                               unsigned short* __restrict__ ws)
{
    const int b = blockIdx.x, t = threadIdx.x;
    if (b < NHEADS * NCH) {                 // W sub-chunk (scaled, f16)
        const float scW = (1.0f / temp[0]) * LOG2E;
        const float* src = W + (size_t)b * OC * HS;
        unsigned short* dst = ws + (size_t)b * SUBELEMS;
        for (int k4 = 0; k4 < 16; ++k4) {
            const int e = k4 * 256 + t;     // 4096 elems
            const int opt = e >> 7, k = e & 127;
            const int kb = k >> 4, hf = (k >> 3) & 1, j = k & 7;
            const int l = hf * 32 + opt;    // opt == la (0..31)
            dst[kb * 512 + l * 8 + j] = f2h(src[e] * scW);
        }
    } else {                                // C sub-chunk -> PV fragment order
        const int b2 = b - NHEADS * NCH;
        const float* src = C + (size_t)b2 * OC * HS;
        unsigned short* dst = ws + WS_C0 + (size_t)b2 * SUBELEMS;
        for (int k4 = 0; k4 < 16; ++k4) {
            const int e = k4 * 256 + t;
            const int opt = e >> 7, a = e & 127;
            const int q = opt >> 4, hf = (opt >> 3) & 1, j = opt & 7;
            const int nt = a >> 5, l = hf * 32 + (a & 31);
            dst[(nt * 2 + q) * 512 + l * 8 + j] = f2h(src[e]);
        }
    }
}

// ============ main: R10 structure + fragment-order LDS + setprio ============
// R11 lesson: direct-from-L2 operands expose load latency (95us); LDS staging
// wins. This round keeps R10's DMA/barrier schedule but stages the
// fragment-order image, making all 32 operand reads/iter linear b128
// (conflict-free) and deleting the XOR-swizzle address VALU.
__global__ __launch_bounds__(256, 2) void vq_main(
    const float* __restrict__ x, const unsigned short* __restrict__ ws,
    float* __restrict__ out)
{
    __shared__ unsigned short wbuf[2][2 * SUBELEMS];   // 32 KB (dbuf, W sub-pair)
    __shared__ unsigned short cbuf[2][2 * SUBELEMS];   // 32 KB (dbuf, C sub-pair)

    const int t = threadIdx.x, l = t & 63, w = t >> 6;
    const int la = l & 31, hf = l >> 5;
    const int b = blockIdx.x;
    const int head = ((b & 7) << 1) | ((b >> 3) & 1);   // 2 heads per XCD
    const int n0 = (b >> 4) * TB;

    const char* gwbase = (const char*)(ws + (size_t)(head * NCH) * SUBELEMS);
    const char* gcbase = (const char*)(ws + WS_C0 + (size_t)(head * NCH) * SUBELEMS);
    const int l8 = l * 8;   // ushort index of this lane's 16B packet

    // ---- prologue DMA: iteration 0's 16KB W-pair + 16KB C-pair ----
    {
        const char* gw = gwbase + w * 4096 + l * 16;
        char* lw = (char*)&wbuf[0][0] + w * 4096;
        const char* gc = gcbase + w * 4096 + l * 16;
        char* lc = (char*)&cbuf[0][0] + w * 4096;
        #pragma unroll
        for (int i = 0; i < 4; ++i) { gll16(gw + i * 1024, lw + i * 1024);
                                      gll16(gc + i * 1024, lc + i * 1024); }
    }

    // ---- x row as f16 B-fragments (32 VGPR) ----
    f16x8 xf[8];
    {
        const float* xr = x + (size_t)(n0 + w * 32 + la) * EMB + head * HS + hf * 8;
        #pragma unroll
        for (int kb = 0; kb < 8; ++kb) {
            const float4 v0 = *(const float4*)(xr + kb * 16);
            const float4 v1 = *(const float4*)(xr + kb * 16 + 4);
            const float vv[8] = {v0.x, v0.y, v0.z, v0.w, v1.x, v1.y, v1.z, v1.w};
            u16x8 hh;
            #pragma unroll
            for (int j = 0; j < 8; ++j) hh[j] = f2h(vv[j]);
            xf[kb] = __builtin_bit_cast(f16x8, hh);
        }
    }

    f32x16 O0 = (f32x16)0.0f, O1 = (f32x16)0.0f, O2 = (f32x16)0.0f, O3 = (f32x16)0.0f;
    float M = -1.0e30f, sacc = 0.0f;

    asm volatile("s_waitcnt vmcnt(0)" ::: "memory");   // iter-0 data landed
    __builtin_amdgcn_s_barrier();

    for (int cc = 0; cc < NITER; ++cc) {
        const int cur = cc & 1;
        // ---- prefetch iteration cc+1 (buffer last read in iter cc-1) ----
        if (cc + 1 < NITER) {
            const char* gw = gwbase + (size_t)(cc + 1) * 16384 + w * 4096 + l * 16;
            char* lw = (char*)&wbuf[cur ^ 1][0] + w * 4096;
            const char* gc = gcbase + (size_t)(cc + 1) * 16384 + w * 4096 + l * 16;
            char* lc = (char*)&cbuf[cur ^ 1][0] + w * 4096;
            #pragma unroll
            for (int i = 0; i < 4; ++i) { gll16(gw + i * 1024, lw + i * 1024);
                                          gll16(gc + i * 1024, lc + i * 1024); }
        }

        // ---- QK^T: S0 (sub0), S1 (sub1); linear b128 reads, 4 MFMA chains ----
        f32x16 s0a = (f32x16)0.0f, s0b = (f32x16)0.0f;
        f32x16 s1a = (f32x16)0.0f, s1b = (f32x16)0.0f;
        const unsigned short* wb0 = &wbuf[cur][0];
        const unsigned short* wb1 = &wbuf[cur][SUBELEMS];
        __builtin_amdgcn_s_setprio(1);
        #pragma unroll
        for (int kb = 0; kb < 8; ++kb) {
            const f16x8 w0 = *(const f16x8*)&wb0[kb * 512 + l8];
            const f16x8 w1 = *(const f16x8*)&wb1[kb * 512 + l8];
            if (kb & 1) { s0b = mfma32h(w0, xf[kb], s0b); s1b = mfma32h(w1, xf[kb], s1b); }
            else        { s0a = mfma32h(w0, xf[kb], s0a); s1a = mfma32h(w1, xf[kb], s1a); }
        }
        __builtin_amdgcn_s_setprio(0);
        f32x16 S0 = s0a + s0b;
        f32x16 S1 = s1a + s1b;

        // ---- online softmax over 64 options (one check per iteration) ----
        float cmax = fmaxf(S0[0], S1[0]);
        #pragma unroll
        for (int i = 1; i < 16; ++i) cmax = fmaxf(fmaxf(cmax, S0[i]), S1[i]);
        cmax = fmaxf(cmax, __shfl_xor(cmax, 32));
        if (__any(cmax > M + THRD)) {          // rare rescale (defer-max, T13)
            const float Mn = fmaxf(M, cmax);
            const float fr = exp2f(M - Mn);    // first iteration: exp2(-1e30)=0
            M = Mn;
            sacc *= fr;
            #pragma unroll
            for (int q = 0; q < 16; ++q) {
                const int row = (q & 3) + 8 * (q >> 2) + 4 * hf;
                const float f = __shfl(fr, row);
                O0[q] *= f; O1[q] *= f; O2[q] *= f; O3[q] *= f;
            }
        }
        #pragma unroll
        for (int q = 0; q < 16; ++q) { S0[q] = exp2f(S0[q] - M); S1[q] = exp2f(S1[q] - M); }
        {   // tree sum over both halves
            float s8[8];
            #pragma unroll
            for (int i = 0; i < 8; ++i)
                s8[i] = (S0[2 * i] + S0[2 * i + 1]) + (S1[2 * i] + S1[2 * i + 1]);
            sacc += ((s8[0] + s8[1]) + (s8[2] + s8[3])) +
                    ((s8[4] + s8[5]) + (s8[6] + s8[7]));
        }

        // ---- P -> f16 A-fragments in-register (verified T12 recipe, x2) ----
        unsigned pk0 = pkrtz(S0[0],  S0[1]),  pk1 = pkrtz(S0[2],  S0[3]);
        unsigned pk2 = pkrtz(S0[4],  S0[5]),  pk3 = pkrtz(S0[6],  S0[7]);
        unsigned pk4 = pkrtz(S0[8],  S0[9]),  pk5 = pkrtz(S0[10], S0[11]);
        unsigned pk6 = pkrtz(S0[12], S0[13]), pk7 = pkrtz(S0[14], S0[15]);
        pl32swap(pk0, pk2); pl32swap(pk1, pk3);
        pl32swap(pk4, pk6); pl32swap(pk5, pk7);
        const f16x8 pa0 = __builtin_bit_cast(f16x8, (u32x4){pk0, pk1, pk2, pk3});
        const f16x8 pa1 = __builtin_bit_cast(f16x8, (u32x4){pk4, pk5, pk6, pk7});
        unsigned qk0 = pkrtz(S1[0],  S1[1]),  qk1 = pkrtz(S1[2],  S1[3]);
        unsigned qk2 = pkrtz(S1[4],  S1[5]),  qk3 = pkrtz(S1[6],  S1[7]);
        unsigned qk4 = pkrtz(S1[8],  S1[9]),  qk5 = pkrtz(S1[10], S1[11]);
        unsigned qk6 = pkrtz(S1[12], S1[13]), qk7 = pkrtz(S1[14], S1[15]);
        pl32swap(qk0, qk2); pl32swap(qk1, qk3);
        pl32swap(qk4, qk6); pl32swap(qk5, qk7);
        const f16x8 pa2 = __builtin_bit_cast(f16x8, (u32x4){qk0, qk1, qk2, qk3});
        const f16x8 pa3 = __builtin_bit_cast(f16x8, (u32x4){qk4, qk5, qk6, qk7});

        // ---- PV: O += P · C ; linear b128 reads from fragment-order LDS ----
        const unsigned short* cb0 = &cbuf[cur][0];
        const unsigned short* cb1 = &cbuf[cur][SUBELEMS];
        __builtin_amdgcn_s_setprio(1);
        #pragma unroll
        for (int nt = 0; nt < 4; ++nt) {
            f32x16& O = (nt == 0) ? O0 : (nt == 1) ? O1 : (nt == 2) ? O2 : O3;
            O = mfma32h(pa0, *(const f16x8*)&cb0[(nt * 2 + 0) * 512 + l8], O);
            O = mfma32h(pa1, *(const f16x8*)&cb0[(nt * 2 + 1) * 512 + l8], O);
            O = mfma32h(pa2, *(const f16x8*)&cb1[(nt * 2 + 0) * 512 + l8], O);
            O = mfma32h(pa3, *(const f16x8*)&cb1[(nt * 2 + 1) * 512 + l8], O);
        }
        __builtin_amdgcn_s_setprio(0);

        // ---- cc+1's DMA had a full 64-option compute to land ----
        asm volatile("s_waitcnt vmcnt(0)" ::: "memory");
        if (cc + 1 < NITER) __builtin_amdgcn_s_barrier();
    }

    // ---- epilogue: normalize by 1/sum, coalesced stores ----
    const float stot = sacc + __shfl_xor(sacc, 32);
    const float rs = 1.0f / stot;
    #pragma unroll
    for (int q = 0; q < 16; ++q) {
        const int row = (q & 3) + 8 * (q >> 2) + 4 * hf;
        const float rq = __shfl(rs, row);
        float* op = out + (size_t)(n0 + w * 32 + row) * EMB + head * HS + la;
        op[0]  = O0[q] * rq;
        op[32] = O1[q] * rq;
        op[64] = O2[q] * rq;
        op[96] = O3[q] * rq;
    }
}

// ============ fallback (Round-2 kernel, no workspace needed) ============
__global__ __launch_bounds__(256, 2) void vq_fwd_mfma(
    const float* __restrict__ x, const float* __restrict__ W,
    const float* __restrict__ C, const float* __restrict__ temp,
    float* __restrict__ out)
{
    __shared__ unsigned short xh_lds[64 * HS];
    __shared__ unsigned short xl_lds[64 * HS];
    __shared__ unsigned short wst[2][64 * HS];
    __shared__ unsigned short p_lds[4][16 * 64];

    const int t = threadIdx.x, l = t & 63, w = t >> 6, lr = l & 15, lk = l >> 4;
    const int b = blockIdx.x;
    const int h = ((b & 7) << 1) | ((b >> 3) & 1);
    const int n0 = (b >> 4) * 64;
    const float invT = 1.0f / temp[0];

    #pragma unroll
    for (int kk = 0; kk < 4; ++kk) {
        const int g = t + 256 * kk;
        const int row = g >> 4, c8 = (g & 15) * 8;
        const float* src = x + (size_t)(n0 + row) * EMB + h * HS + c8;
        const float4 v0 = *(const float4*)src;
        const float4 v1 = *(const float4*)(src + 4);
        float vv[8] = {v0.x, v0.y, v0.z, v0.w, v1.x, v1.y, v1.z, v1.w};
        u16x8 hh, ll;
        #pragma unroll
        for (int j = 0; j < 8; ++j) {
            const unsigned short hb = f2bf(vv[j]);
            hh[j] = hb; ll[j] = f2bf(vv[j] - bf2f(hb));
        }
        const int idx = row * HS + (c8 ^ ((row & 7) << 3));
        *(u16x8*)&xh_lds[idx] = hh;
        *(u16x8*)&xl_lds[idx] = ll;
    }

    f32x4 acc[32];
    #pragma unroll
    for (int i = 0; i < 32; ++i) acc[i] = f32x4{0.f, 0.f, 0.f, 0.f};
    bf16x8 axh[4], axl[4];

    #pragma unroll
    for (int c = 0; c < 8; ++c) {
        if (c) __syncthreads();
        #pragma unroll
        for (int kk = 0; kk < 4; ++kk) {
            const int g = t + 256 * kk;
            const int row = g >> 4, c8 = (g & 15) * 8;
            const float* src = W + ((size_t)h * NOPT + c * 64 + row) * HS + c8;
            const float4 v0 = *(const float4*)src;
            const float4 v1 = *(const float4*)(src + 4);
            float vv[8] = {v0.x, v0.y, v0.z, v0.w, v1.x, v1.y, v1.z, v1.w};
            u16x8 hh, ll;
            #pragma unroll
            for (int j = 0; j < 8; ++j) {
                const unsigned short hb = f2bf(vv[j]);
                hh[j] = hb; ll[j] = f2bf(vv[j] - bf2f(hb));
            }
            const int idx = row * HS + (c8 ^ ((row & 7) << 3));
            *(u16x8*)&wst[0][idx] = hh;
            *(u16x8*)&wst[1][idx] = ll;
        }
        __syncthreads();
        if (c == 0) {
            const int arow = w * 16 + lr;
            #pragma unroll
            for (int ks = 0; ks < 4; ++ks) {
                const int ai = arow * HS + ((lk * 8 + ks * 32) ^ ((arow & 7) << 3));
                axh[ks] = *(const bf16x8*)&xh_lds[ai];
                axl[ks] = *(const bf16x8*)&xl_lds[ai];
            }
        }
        #pragma unroll
        for (int nt = 0; nt < 4; ++nt) {
            const int brow = nt * 16 + lr;
            #pragma unroll
            for (int ks = 0; ks < 4; ++ks) {
                const int bi = brow * HS + ((lk * 8 + ks * 32) ^ ((brow & 7) << 3));
                const bf16x8 bh = *(const bf16x8*)&wst[0][bi];
                const bf16x8 bl = *(const bf16x8*)&wst[1][bi];
                acc[c*4+nt] = __builtin_amdgcn_mfma_f32_16x16x32_bf16(axh[ks], bh, acc[c*4+nt], 0, 0, 0);
                acc[c*4+nt] = __builtin_amdgcn_mfma_f32_16x16x32_bf16(axl[ks], bh, acc[c*4+nt], 0, 0, 0);
                acc[c*4+nt] = __builtin_amdgcn_mfma_f32_16x16x32_bf16(axh[ks], bl, acc[c*4+nt], 0, 0, 0);
            }
        }
    }

    float mx[4], rsn[4];
    #pragma unroll
    for (int r = 0; r < 4; ++r) {
        float m = -3.0e38f;
        #pragma unroll
        for (int i = 0; i < 32; ++i) m = fmaxf(m, acc[i][r]);
        m *= invT;
        #pragma unroll
        for (int s = 1; s < 16; s <<= 1) m = fmaxf(m, __shfl_xor(m, s));
        float sum = 0.f;
        #pragma unroll
        for (int i = 0; i < 32; ++i) sum += exp2f((acc[i][r] * invT - m) * LOG2E);
        #pragma unroll
        for (int s = 1; s < 16; s <<= 1) sum += __shfl_xor(sum, s);
        mx[r] = m; rsn[r] = 1.0f / sum;
    }

    f32x4 oacc[8];
    #pragma unroll
    for (int i = 0; i < 8; ++i) oacc[i] = f32x4{0.f, 0.f, 0.f, 0.f};
    const int pr_ = t & 31, ag = t >> 5;
    #pragma unroll
    for (int c = 0; c < 8; ++c) {
        __syncthreads();
        {
            const float* c0p = C + ((size_t)h * NOPT + c * 64 + 2 * pr_) * HS + ag * 16;
            float va[16], vb[16];
            #pragma unroll
            for (int q = 0; q < 4; ++q) {
                const float4 u0 = ((const float4*)c0p)[q];
                const float4 u1 = ((const float4*)(c0p + HS))[q];
                va[q*4+0] = u0.x; va[q*4+1] = u0.y; va[q*4+2] = u0.z; va[q*4+3] = u0.w;
                vb[q*4+0] = u1.x; vb[q*4+1] = u1.y; vb[q*4+2] = u1.z; vb[q*4+3] = u1.w;
            }
            unsigned* ct32 = (unsigned*)&wst[0][0];
            #pragma unroll
            for (int j = 0; j < 16; ++j) {
                const int a = ag * 16 + j;
                const unsigned pkv = (unsigned)f2bf(va[j]) | ((unsigned)f2bf(vb[j]) << 16);
                ct32[a * 32 + (pr_ ^ ((a & 7) << 2))] = pkv;
            }
        }
        #pragma unroll
        for (int nt = 0; nt < 4; ++nt) {
            #pragma unroll
            for (int r = 0; r < 4; ++r) {
                const float p = exp2f((acc[c*4+nt][r] * invT - mx[r]) * LOG2E);
                const int prow = lk * 4 + r;
                const int pcol = nt * 16 + lr;
                p_lds[w][prow * 64 + (pcol ^ ((prow & 7) << 3))] = f2bf(p);
            }
        }
        __syncthreads();
        #pragma unroll
        for (int ks = 0; ks < 2; ++ks) {
            const int ai = lr * 64 + ((lk * 8 + ks * 32) ^ ((lr & 7) << 3));
            const bf16x8 pa = *(const bf16x8*)&p_lds[w][ai];
            #pragma unroll
            for (int nt = 0; nt < 8; ++nt) {
                const int brow = nt * 16 + lr;
                const int bi = brow * 64 + ((lk * 8 + ks * 32) ^ ((brow & 7) << 3));
                const bf16x8 cbv = *(const bf16x8*)&wst[0][bi];
                oacc[nt] = __builtin_amdgcn_mfma_f32_16x16x32_bf16(pa, cbv, oacc[nt], 0, 0, 0);
            }
        }
    }

    #pragma unroll
    for (int nt = 0; nt < 8; ++nt) {
        #pragma unroll
        for (int r = 0; r < 4; ++r) {
            const int tok = n0 + w * 16 + lk * 4 + r;
            out[(size_t)tok * EMB + h * HS + nt * 16 + lr] = oacc[nt][r] * rsn[r];
        }
    }
}

extern "C" void kernel_launch(void* const* d_in, const int* in_sizes, int n_in,
                              void* d_out, int out_size, void* d_ws, size_t ws_size,
                              hipStream_t stream) {
    const float* x = (const float*)d_in[0];
    const float* W = (const float*)d_in[1];
    const float* C = (const float*)d_in[2];
    const float* T = (const float*)d_in[3];
    float* out     = (float*)d_out;

    const int ntok = in_sizes[0] / EMB;   // 8192

    if (ws_size >= WS_TOTAL_BYTES) {
        hipLaunchKernelGGL(vq_prep, dim3(NHEADS * NCH * 2), dim3(256), 0, stream,
                           W, C, T, (unsigned short*)d_ws);
        const int nblk = (ntok / TB) * NHEADS;   // 1024
        hipLaunchKernelGGL(vq_main, dim3(nblk), dim3(256), 0, stream,
                           x, (const unsigned short*)d_ws, out);
    } else {
        const int nblk = (ntok / 64) * NHEADS;   // 2048
        hipLaunchKernelGGL(vq_fwd_mfma, dim3(nblk), dim3(256), 0, stream,
                           x, W, C, T, out);
    }
}

// Round 13
// 71.291 us; speedup vs baseline: 1.3386x; 1.0175x over previous
//
#include <hip/hip_runtime.h>
#include <math.h>

#define NHEADS 16
#define HS     128
#define NOPT   512
#define TB     128      // tokens per block (4 waves x 32)
#define OC     32       // options per image sub-chunk
#define NCH    16       // sub-chunks per head
#define NITER  16       // one sub-chunk (32 options) per iteration
#define EMB    2048
#define LOG2E  1.44269504088896340736f
#define THRD   11.0f    // defer-max threshold (log2 units)

typedef short bf16x8 __attribute__((ext_vector_type(8)));
typedef _Float16 f16x8 __attribute__((ext_vector_type(8)));
typedef unsigned short u16x8 __attribute__((ext_vector_type(8)));
typedef float f32x4 __attribute__((ext_vector_type(4)));
typedef float f32x16 __attribute__((ext_vector_type(16)));
typedef unsigned u32x4 __attribute__((ext_vector_type(4)));

__device__ __forceinline__ unsigned short f2bf(float f) {
    union { float f; unsigned u; } v; v.f = f;
    unsigned r = v.u + 0x7FFFu + ((v.u >> 16) & 1u);
    return (unsigned short)(r >> 16);
}
__device__ __forceinline__ float bf2f(unsigned short h) {
    union { unsigned u; float f; } v; v.u = ((unsigned)h) << 16;
    return v.f;
}
__device__ __forceinline__ unsigned short f2h(float f) {   // RNE f32->f16 bits
    const _Float16 h = (_Float16)f;
    return __builtin_bit_cast(unsigned short, h);
}
__device__ __forceinline__ void gll16(const void* gptr, void* lptr) {
    __builtin_amdgcn_global_load_lds(
        (const __attribute__((address_space(1))) void*)gptr,
        (__attribute__((address_space(3))) void*)lptr,
        16, 0, 0);
}
__device__ __forceinline__ unsigned pkrtz(float lo, float hi) {
    unsigned r;
    asm("v_cvt_pkrtz_f16_f32 %0, %1, %2" : "=v"(r) : "v"(lo), "v"(hi));
    return r;
}
__device__ __forceinline__ void pl32swap(unsigned &a, unsigned &b) {
    asm volatile("v_permlane32_swap_b32 %0, %1" : "+v"(a), "+v"(b));
}
__device__ __forceinline__ f32x16 mfma32h(f16x8 a, f16x8 b, f32x16 c) {
    return __builtin_amdgcn_mfma_f32_32x32x16_f16(a, b, c, 0, 0, 0);
}

// ------------- workspace image layout (ushorts, f16 bits), FRAGMENT ORDER ----
// (identical to R11/R12, verified)
// W': [h][sub][kb][lane][8]     pre-scaled by invT*log2e. 8 KB / sub-chunk.
// C : [h][sub][nt*2+q][lane][8] PV B-operand packets.     8 KB / sub-chunk.
#define SUBELEMS 4096
#define WS_C0  (NHEADS * NCH * SUBELEMS)
#define WS_TOTAL_BYTES ((size_t)(WS_C0 + NHEADS * NCH * SUBELEMS) * 2) // 4 MB

// ============ prep: f32 -> fragment-order f16 images (vectorized) ============
// Same bit-exact output as R12's prep; each thread now builds whole 16B packets
// (u16x8 stores) instead of 16 scalar 2B stores.
__global__ __launch_bounds__(256) void vq_prep(const float* __restrict__ W,
                                               const float* __restrict__ C,
                                               const float* __restrict__ temp,
                                               unsigned short* __restrict__ ws)
{
    const int b = blockIdx.x, t = threadIdx.x;
    if (b < NHEADS * NCH) {                 // W sub-chunk (scaled, f16)
        const float scW = (1.0f / temp[0]) * LOG2E;
        const float* src = W + (size_t)b * OC * HS;
        unsigned short* dst = ws + (size_t)b * SUBELEMS;
        #pragma unroll
        for (int i = 0; i < 2; ++i) {       // 512 packets, 2 per thread
            const int pid = i * 256 + t;
            const int kb = pid >> 6, l = pid & 63;
            const int base = (l & 31) * 128 + kb * 16 + (l >> 5) * 8;
            const float4 v0 = *(const float4*)(src + base);
            const float4 v1 = *(const float4*)(src + base + 4);
            u16x8 hh;
            hh[0] = f2h(v0.x * scW); hh[1] = f2h(v0.y * scW);
            hh[2] = f2h(v0.z * scW); hh[3] = f2h(v0.w * scW);
            hh[4] = f2h(v1.x * scW); hh[5] = f2h(v1.y * scW);
            hh[6] = f2h(v1.z * scW); hh[7] = f2h(v1.w * scW);
            *(u16x8*)&dst[kb * 512 + l * 8] = hh;
        }
    } else {                                // C sub-chunk -> PV fragment order
        const int b2 = b - NHEADS * NCH;
        const float* src = C + (size_t)b2 * OC * HS;
        unsigned short* dst = ws + WS_C0 + (size_t)b2 * SUBELEMS;
        #pragma unroll
        for (int i = 0; i < 2; ++i) {
            const int pid = i * 256 + t;
            const int ntq = pid >> 6, l = pid & 63;
            const int nt = ntq >> 1, q = ntq & 1;
            const int a = nt * 32 + (l & 31);
            const int o0 = q * 16 + (l >> 5) * 8;
            u16x8 hh;
            #pragma unroll
            for (int j = 0; j < 8; ++j) hh[j] = f2h(src[(o0 + j) * 128 + a]);
            *(u16x8*)&dst[ntq * 512 + l * 8] = hh;
        }
    }
}

// ============ main: 32-opt iters, 32KB LDS, ~140 regs -> 3 waves/SIMD =======
// R12 post-mortem: regs (168) allowed 3 waves/SIMD but LDS (64KB) capped 2
// blocks/CU. This round: LDS 32KB (dbuf of one 8KB W + 8KB C sub-chunk) and
// single-chain QK (frees sa/sb, ~136 total regs) -> registers allow 3, LDS
// allows 5 -> expect 3 blocks/CU. No launch_bounds forcing (R5/R9 lesson).
__global__ __launch_bounds__(256, 2) void vq_main(
    const float* __restrict__ x, const unsigned short* __restrict__ ws,
    float* __restrict__ out)
{
    __shared__ unsigned short wbuf[2][SUBELEMS];   // 16 KB (dbuf W sub-chunk)
    __shared__ unsigned short cbuf[2][SUBELEMS];   // 16 KB (dbuf C sub-chunk)

    const int t = threadIdx.x, l = t & 63, w = t >> 6;
    const int la = l & 31, hf = l >> 5;
    const int b = blockIdx.x;
    const int head = ((b & 7) << 1) | ((b >> 3) & 1);   // 2 heads per XCD
    const int n0 = (b >> 4) * TB;

    const char* gwbase = (const char*)(ws + (size_t)(head * NCH) * SUBELEMS);
    const char* gcbase = (const char*)(ws + WS_C0 + (size_t)(head * NCH) * SUBELEMS);
    const int l8 = l * 8;   // ushort index of this lane's 16B packet

    // ---- prologue DMA: sub-chunk 0 (8KB W + 8KB C; 2KB per wave each) ----
    {
        const char* gw = gwbase + w * 2048 + l * 16;
        char* lw = (char*)&wbuf[0][0] + w * 2048;
        const char* gc = gcbase + w * 2048 + l * 16;
        char* lc = (char*)&cbuf[0][0] + w * 2048;
        gll16(gw, lw); gll16(gw + 1024, lw + 1024);
        gll16(gc, lc); gll16(gc + 1024, lc + 1024);
    }

    // ---- x row as f16 B-fragments (32 VGPR) ----
    f16x8 xf[8];
    {
        const float* xr = x + (size_t)(n0 + w * 32 + la) * EMB + head * HS + hf * 8;
        #pragma unroll
        for (int kb = 0; kb < 8; ++kb) {
            const float4 v0 = *(const float4*)(xr + kb * 16);
            const float4 v1 = *(const float4*)(xr + kb * 16 + 4);
            const float vv[8] = {v0.x, v0.y, v0.z, v0.w, v1.x, v1.y, v1.z, v1.w};
            u16x8 hh;
            #pragma unroll
            for (int j = 0; j < 8; ++j) hh[j] = f2h(vv[j]);
            xf[kb] = __builtin_bit_cast(f16x8, hh);
        }
    }

    f32x16 O0 = (f32x16)0.0f, O1 = (f32x16)0.0f, O2 = (f32x16)0.0f, O3 = (f32x16)0.0f;
    float M = -1.0e30f, sacc = 0.0f;

    asm volatile("s_waitcnt vmcnt(0)" ::: "memory");   // sub-chunk 0 landed
    __builtin_amdgcn_s_barrier();

    for (int cc = 0; cc < NITER; ++cc) {
        const int cur = cc & 1;
        // ---- prefetch sub-chunk cc+1 (buffer last read in iter cc-1) ----
        if (cc + 1 < NITER) {
            const char* gw = gwbase + (size_t)(cc + 1) * 8192 + w * 2048 + l * 16;
            char* lw = (char*)&wbuf[cur ^ 1][0] + w * 2048;
            const char* gc = gcbase + (size_t)(cc + 1) * 8192 + w * 2048 + l * 16;
            char* lc = (char*)&cbuf[cur ^ 1][0] + w * 2048;
            gll16(gw, lw); gll16(gw + 1024, lw + 1024);
            gll16(gc, lc); gll16(gc + 1024, lc + 1024);
        }

        // ---- QK^T: single accumulation chain (8 MFMAs), linear b128 reads ----
        f32x16 S = (f32x16)0.0f;
        const unsigned short* wb = &wbuf[cur][0];
        __builtin_amdgcn_s_setprio(1);
        #pragma unroll
        for (int kb = 0; kb < 8; ++kb)
            S = mfma32h(*(const f16x8*)&wb[kb * 512 + l8], xf[kb], S);
        __builtin_amdgcn_s_setprio(0);

        // ---- online softmax over 32 options (per token = per lane) ----
        float cmax = fmaxf(S[0], S[1]);
        #pragma unroll
        for (int i = 2; i < 16; i += 2) cmax = fmaxf(fmaxf(cmax, S[i]), S[i + 1]);
        cmax = fmaxf(cmax, __shfl_xor(cmax, 32));
        if (__any(cmax > M + THRD)) {          // rare rescale (defer-max, T13)
            const float Mn = fmaxf(M, cmax);
            const float fr = exp2f(M - Mn);    // first iteration: exp2(-1e30)=0
            M = Mn;
            sacc *= fr;
            #pragma unroll
            for (int q = 0; q < 16; ++q) {
                const int row = (q & 3) + 8 * (q >> 2) + 4 * hf;
                const float f = __shfl(fr, row);
                O0[q] *= f; O1[q] *= f; O2[q] *= f; O3[q] *= f;
            }
        }
        #pragma unroll
        for (int q = 0; q < 16; ++q) S[q] = exp2f(S[q] - M);
        {   // tree sum
            float s8[8];
            #pragma unroll
            for (int i = 0; i < 8; ++i) s8[i] = S[2 * i] + S[2 * i + 1];
            sacc += ((s8[0] + s8[1]) + (s8[2] + s8[3])) +
                    ((s8[4] + s8[5]) + (s8[6] + s8[7]));
        }

        // ---- P -> f16 A-fragments in-register (verified T12 recipe) ----
        unsigned pk0 = pkrtz(S[0],  S[1]),  pk1 = pkrtz(S[2],  S[3]);
        unsigned pk2 = pkrtz(S[4],  S[5]),  pk3 = pkrtz(S[6],  S[7]);
        unsigned pk4 = pkrtz(S[8],  S[9]),  pk5 = pkrtz(S[10], S[11]);
        unsigned pk6 = pkrtz(S[12], S[13]), pk7 = pkrtz(S[14], S[15]);
        pl32swap(pk0, pk2); pl32swap(pk1, pk3);
        pl32swap(pk4, pk6); pl32swap(pk5, pk7);
        const f16x8 pa0 = __builtin_bit_cast(f16x8, (u32x4){pk0, pk1, pk2, pk3});
        const f16x8 pa1 = __builtin_bit_cast(f16x8, (u32x4){pk4, pk5, pk6, pk7});

        // ---- PV: O += P · C ; 8 MFMAs, 4 independent chains ----
        const unsigned short* cb = &cbuf[cur][0];
        __builtin_amdgcn_s_setprio(1);
        #pragma unroll
        for (int nt = 0; nt < 4; ++nt) {
            f32x16& O = (nt == 0) ? O0 : (nt == 1) ? O1 : (nt == 2) ? O2 : O3;
            O = mfma32h(pa0, *(const f16x8*)&cb[(nt * 2 + 0) * 512 + l8], O);
            O = mfma32h(pa1, *(const f16x8*)&cb[(nt * 2 + 1) * 512 + l8], O);
        }
        __builtin_amdgcn_s_setprio(0);

        // ---- cc+1's DMA had a full sub-chunk compute to land ----
        asm volatile("s_waitcnt vmcnt(0)" ::: "memory");
        if (cc + 1 < NITER) __builtin_amdgcn_s_barrier();
    }

    // ---- epilogue: normalize by 1/sum, coalesced stores ----
    const float stot = sacc + __shfl_xor(sacc, 32);
    const float rs = 1.0f / stot;
    #pragma unroll
    for (int q = 0; q < 16; ++q) {
        const int row = (q & 3) + 8 * (q >> 2) + 4 * hf;
        const float rq = __shfl(rs, row);
        float* op = out + (size_t)(n0 + w * 32 + row) * EMB + head * HS + la;
        op[0]  = O0[q] * rq;
        op[32] = O1[q] * rq;
        op[64] = O2[q] * rq;
        op[96] = O3[q] * rq;
    }
}

// ============ fallback (Round-2 kernel, no workspace needed) ============
__global__ __launch_bounds__(256, 2) void vq_fwd_mfma(
    const float* __restrict__ x, const float* __restrict__ W,
    const float* __restrict__ C, const float* __restrict__ temp,
    float* __restrict__ out)
{
    __shared__ unsigned short xh_lds[64 * HS];
    __shared__ unsigned short xl_lds[64 * HS];
    __shared__ unsigned short wst[2][64 * HS];
    __shared__ unsigned short p_lds[4][16 * 64];

    const int t = threadIdx.x, l = t & 63, w = t >> 6, lr = l & 15, lk = l >> 4;
    const int b = blockIdx.x;
    const int h = ((b & 7) << 1) | ((b >> 3) & 1);
    const int n0 = (b >> 4) * 64;
    const float invT = 1.0f / temp[0];

    #pragma unroll
    for (int kk = 0; kk < 4; ++kk) {
        const int g = t + 256 * kk;
        const int row = g >> 4, c8 = (g & 15) * 8;
        const float* src = x + (size_t)(n0 + row) * EMB + h * HS + c8;
        const float4 v0 = *(const float4*)src;
        const float4 v1 = *(const float4*)(src + 4);
        float vv[8] = {v0.x, v0.y, v0.z, v0.w, v1.x, v1.y, v1.z, v1.w};
        u16x8 hh, ll;
        #pragma unroll
        for (int j = 0; j < 8; ++j) {
            const unsigned short hb = f2bf(vv[j]);
            hh[j] = hb; ll[j] = f2bf(vv[j] - bf2f(hb));
        }
        const int idx = row * HS + (c8 ^ ((row & 7) << 3));
        *(u16x8*)&xh_lds[idx] = hh;
        *(u16x8*)&xl_lds[idx] = ll;
    }

    f32x4 acc[32];
    #pragma unroll
    for (int i = 0; i < 32; ++i) acc[i] = f32x4{0.f, 0.f, 0.f, 0.f};
    bf16x8 axh[4], axl[4];

    #pragma unroll
    for (int c = 0; c < 8; ++c) {
        if (c) __syncthreads();
        #pragma unroll
        for (int kk = 0; kk < 4; ++kk) {
            const int g = t + 256 * kk;
            const int row = g >> 4, c8 = (g & 15) * 8;
            const float* src = W + ((size_t)h * NOPT + c * 64 + row) * HS + c8;
            const float4 v0 = *(const float4*)src;
            const float4 v1 = *(const float4*)(src + 4);
            float vv[8] = {v0.x, v0.y, v0.z, v0.w, v1.x, v1.y, v1.z, v1.w};
            u16x8 hh, ll;
            #pragma unroll
            for (int j = 0; j < 8; ++j) {
                const unsigned short hb = f2bf(vv[j]);
                hh[j] = hb; ll[j] = f2bf(vv[j] - bf2f(hb));
            }
            const int idx = row * HS + (c8 ^ ((row & 7) << 3));
            *(u16x8*)&wst[0][idx] = hh;
            *(u16x8*)&wst[1][idx] = ll;
        }
        __syncthreads();
        if (c == 0) {
            const int arow = w * 16 + lr;
            #pragma unroll
            for (int ks = 0; ks < 4; ++ks) {
                const int ai = arow * HS + ((lk * 8 + ks * 32) ^ ((arow & 7) << 3));
                axh[ks] = *(const bf16x8*)&xh_lds[ai];
                axl[ks] = *(const bf16x8*)&xl_lds[ai];
            }
        }
        #pragma unroll
        for (int nt = 0; nt < 4; ++nt) {
            const int brow = nt * 16 + lr;
            #pragma unroll
            for (int ks = 0; ks < 4; ++ks) {
                const int bi = brow * HS + ((lk * 8 + ks * 32) ^ ((brow & 7) << 3));
                const bf16x8 bh = *(const bf16x8*)&wst[0][bi];
                const bf16x8 bl = *(const bf16x8*)&wst[1][bi];
                acc[c*4+nt] = __builtin_amdgcn_mfma_f32_16x16x32_bf16(axh[ks], bh, acc[c*4+nt], 0, 0, 0);
                acc[c*4+nt] = __builtin_amdgcn_mfma_f32_16x16x32_bf16(axl[ks], bh, acc[c*4+nt], 0, 0, 0);
                acc[c*4+nt] = __builtin_amdgcn_mfma_f32_16x16x32_bf16(axh[ks], bl, acc[c*4+nt], 0, 0, 0);
            }
        }
    }

    float mx[4], rsn[4];
    #pragma unroll
    for (int r = 0; r < 4; ++r) {
        float m = -3.0e38f;
        #pragma unroll
        for (int i = 0; i < 32; ++i) m = fmaxf(m, acc[i][r]);
        m *= invT;
        #pragma unroll
        for (int s = 1; s < 16; s <<= 1) m = fmaxf(m, __shfl_xor(m, s));
        float sum = 0.f;
        #pragma unroll
        for (int i = 0; i < 32; ++i) sum += exp2f((acc[i][r] * invT - m) * LOG2E);
        #pragma unroll
        for (int s = 1; s < 16; s <<= 1) sum += __shfl_xor(sum, s);
        mx[r] = m; rsn[r] = 1.0f / sum;
    }

    f32x4 oacc[8];
    #pragma unroll
    for (int i = 0; i < 8; ++i) oacc[i] = f32x4{0.f, 0.f, 0.f, 0.f};
    const int pr_ = t & 31, ag = t >> 5;
    #pragma unroll
    for (int c = 0; c < 8; ++c) {
        __syncthreads();
        {
            const float* c0p = C + ((size_t)h * NOPT + c * 64 + 2 * pr_) * HS + ag * 16;
            float va[16], vb[16];
            #pragma unroll
            for (int q = 0; q < 4; ++q) {
                const float4 u0 = ((const float4*)c0p)[q];
                const float4 u1 = ((const float4*)(c0p + HS))[q];
                va[q*4+0] = u0.x; va[q*4+1] = u0.y; va[q*4+2] = u0.z; va[q*4+3] = u0.w;
                vb[q*4+0] = u1.x; vb[q*4+1] = u1.y; vb[q*4+2] = u1.z; vb[q*4+3] = u1.w;
            }
            unsigned* ct32 = (unsigned*)&wst[0][0];
            #pragma unroll
            for (int j = 0; j < 16; ++j) {
                const int a = ag * 16 + j;
                const unsigned pkv = (unsigned)f2bf(va[j]) | ((unsigned)f2bf(vb[j]) << 16);
                ct32[a * 32 + (pr_ ^ ((a & 7) << 2))] = pkv;
            }
        }
        #pragma unroll
        for (int nt = 0; nt < 4; ++nt) {
            #pragma unroll
            for (int r = 0; r < 4; ++r) {
                const float p = exp2f((acc[c*4+nt][r] * invT - mx[r]) * LOG2E);
                const int prow = lk * 4 + r;
                const int pcol = nt * 16 + lr;
                p_lds[w][prow * 64 + (pcol ^ ((prow & 7) << 3))] = f2bf(p);
            }
        }
        __syncthreads();
        #pragma unroll
        for (int ks = 0; ks < 2; ++ks) {
            const int ai = lr * 64 + ((lk * 8 + ks * 32) ^ ((lr & 7) << 3));
            const bf16x8 pa = *(const bf16x8*)&p_lds[w][ai];
            #pragma unroll
            for (int nt = 0; nt < 8; ++nt) {
                const int brow = nt * 16 + lr;
                const int bi = brow * 64 + ((lk * 8 + ks * 32) ^ ((brow & 7) << 3));
                const bf16x8 cbv = *(const bf16x8*)&wst[0][bi];
                oacc[nt] = __builtin_amdgcn_mfma_f32_16x16x32_bf16(pa, cbv, oacc[nt], 0, 0, 0);
            }
        }
    }

    #pragma unroll
    for (int nt = 0; nt < 8; ++nt) {
        #pragma unroll
        for (int r = 0; r < 4; ++r) {
            const int tok = n0 + w * 16 + lk * 4 + r;
            out[(size_t)tok * EMB + h * HS + nt * 16 + lr] = oacc[nt][r] * rsn[r];
        }
    }
}

extern "C" void kernel_launch(void* const* d_in, const int* in_sizes, int n_in,
                              void* d_out, int out_size, void* d_ws, size_t ws_size,
                              hipStream_t stream) {
    const float* x = (const float*)d_in[0];
    const float* W = (const float*)d_in[1];
    const float* C = (const float*)d_in[2];
    const float* T = (const float*)d_in[3];
    float* out     = (float*)d_out;

    const int ntok = in_sizes[0] / EMB;   // 8192

    if (ws_size >= WS_TOTAL_BYTES) {
        hipLaunchKernelGGL(vq_prep, dim3(NHEADS * NCH * 2), dim3(256), 0, stream,
                           W, C, T, (unsigned short*)d_ws);
        const int nblk = (ntok / TB) * NHEADS;   // 1024
        hipLaunchKernelGGL(vq_main, dim3(nblk), dim3(256), 0, stream,
                           x, (const unsigned short*)d_ws, out);
    } else {
        const int nblk = (ntok / 64) * NHEADS;   // 2048
        hipLaunchKernelGGL(vq_fwd_mfma, dim3(nblk), dim3(256), 0, stream,
                           x, W, C, T, out);
    }
}